// Round 15
// baseline (62.913 us; speedup 1.0000x reference)
//
#include <hip/hip_runtime.h>
#include <hip/hip_bf16.h>
#include <math.h>

#define BATCH 4
#define CH    64
#define NPOS  4096   // 64*64
#define NGRP  8
#define CPG   8      // CH / NGRP
#define GEPS  1e-5f
#define NSPLIT 8     // K-dim split of attention
#define LOG2E 1.4426950408889634f

typedef __attribute__((ext_vector_type(8))) short bf16x8;   // 8 bf16 = 4 VGPRs
typedef __attribute__((ext_vector_type(4))) float f32x4;

// float -> bf16 bits (round-to-nearest-even)
__device__ __forceinline__ ushort f2bf(float f) {
    union { float f; uint32_t u; } v; v.f = f;
    uint32_t r = v.u + 0x7fffu + ((v.u >> 16) & 1u);
    return (ushort)(r >> 16);
}
__device__ __forceinline__ float bf2f(ushort u) {
    union { uint32_t u; float f; } v; v.u = ((uint32_t)u) << 16; return v.f;
}

// XOR swizzle within a 128B row: logical (row, byteInRow) -> physical byte offset
__device__ __forceinline__ uint32_t swz(uint32_t row, uint32_t byteInRow) {
    return (row << 7) + (byteInRow ^ ((row & 7u) << 4));
}

// 16B ds_read of an MFMA fragment slice
__device__ __forceinline__ bf16x8 ldfrag(const ushort* base, int row, int kbyte) {
    return *(const bf16x8*)((const char*)base + swz(row, kbyte));
}

// ---------------------------------------------------------------------------
// Kernel 1: GroupNorm partial sums. Grid 256: block = (bg, slice of 4096).
// ---------------------------------------------------------------------------
__global__ __launch_bounds__(256) void gn_part_kernel(const float* __restrict__ x,
                                                      float2* __restrict__ part) {
    const int blk = blockIdx.x;                      // bg*8 + slice
    const float4* xp4 = (const float4*)(x + (size_t)blk * 4096);
    float s1 = 0.f, s2 = 0.f;
    for (int i = threadIdx.x; i < 1024; i += 256) {
        float4 t = xp4[i];
        s1 += t.x + t.y + t.z + t.w;
        s2 += t.x * t.x + t.y * t.y + t.z * t.z + t.w * t.w;
    }
    __shared__ float sh1[256], sh2[256];
    const int tid = threadIdx.x;
    sh1[tid] = s1; sh2[tid] = s2;
    __syncthreads();
    for (int off = 128; off > 0; off >>= 1) {
        if (tid < off) { sh1[tid] += sh1[tid + off]; sh2[tid] += sh2[tid + off]; }
        __syncthreads();
    }
    if (tid == 0) { float2 r; r.x = sh1[0]; r.y = sh2[0]; part[blk] = r; }
}

// ---------------------------------------------------------------------------
// Kernel 2: fused GN-finish + GroupNorm-apply + ONE of {q,k,v} 1x1 conv.
// Grid 768. Outputs in FRAGMENT-BLOCKED layout (contiguous lane-linear 1KB
// chunks per MFMA fragment):
//   Q_blk[b][qgrp(128 of 32q)][qgi(2)][h(2)][lane(64)][8]
//   K_blk[b][kt(64)][nt(4)][h(2)][lane(64)][8]
//   V_blk[b][kt(64)][ct(4)][h(2)][lane(64)][8]
// q folds bias and 0.125*log2e (exp2-domain softmax).
// ---------------------------------------------------------------------------
__global__ __launch_bounds__(256) void qkv_mfma_kernel(
    const float* __restrict__ x, const float2* __restrict__ part,
    const float* __restrict__ gamma, const float* __restrict__ beta,
    const float* __restrict__ Wq, const float* __restrict__ bq,
    const float* __restrict__ Wk, const float* __restrict__ bk,
    const float* __restrict__ Wv, const float* __restrict__ bv,
    ushort* __restrict__ qg, ushort* __restrict__ kg, ushort* __restrict__ vg)
{
    __shared__ ushort xn[64 * 64];     // [n][c] swizzled bf16
    __shared__ ushort Wl[64 * 64];     // W [o][c] swizzled bf16
    __shared__ ushort ob[64 * 64];     // output bounce
    __shared__ float st[16];           // 8 groups * {mean, rstd} for this b

    const int tid = threadIdx.x;
    const int w = tid >> 6, lane = tid & 63, g = lane >> 4, q16 = lane & 15;
    const int m = blockIdx.x >> 8;               // 0=q 1=k 2=v
    const int bidx = blockIdx.x & 255;
    const int b = bidx >> 6, n0 = (bidx & 63) << 6;

    const float* W = (m == 0) ? Wq : (m == 1) ? Wk : Wv;

    {
        const int row = tid >> 2, cb = (tid & 3) << 4;
#pragma unroll
        for (int j = 0; j < 4; ++j) {
            float4 v = *(const float4*)(W + row * 64 + cb + j * 4);
            ushort4 h; h.x = f2bf(v.x); h.y = f2bf(v.y); h.z = f2bf(v.z); h.w = f2bf(v.w);
            *(ushort4*)((char*)Wl + swz(row, (cb + j * 4) * 2)) = h;
        }
    }
    if (tid < 64) {
        float2 p = part[b * 64 + tid];
        float s1 = p.x, s2 = p.y;
        s1 += __shfl_xor(s1, 1); s2 += __shfl_xor(s2, 1);
        s1 += __shfl_xor(s1, 2); s2 += __shfl_xor(s2, 2);
        s1 += __shfl_xor(s1, 4); s2 += __shfl_xor(s2, 4);
        if ((tid & 7) == 0) {
            const float inv = 1.0f / (float)(CPG * NPOS);
            float mean = s1 * inv;
            float var  = s2 * inv - mean * mean;
            st[(tid >> 3) * 2]     = mean;
            st[(tid >> 3) * 2 + 1] = rsqrtf(var + GEPS);
        }
    }
    __syncthreads();

    {
        const int c = tid >> 2, nb = (tid & 3) << 4;
        const float mean = st[(c >> 3) * 2];
        const float rstd = st[(c >> 3) * 2 + 1];
        const float gmm = gamma[c] * rstd;
        const float btt = beta[c] - mean * gmm;
        const float* xp = x + (((size_t)(b * CH + c)) << 12) + n0 + nb;
#pragma unroll
        for (int j = 0; j < 4; ++j) {
            float4 v = *(const float4*)(xp + j * 4);
            float vv[4] = {v.x, v.y, v.z, v.w};
#pragma unroll
            for (int e = 0; e < 4; ++e) {
                int n = nb + j * 4 + e;
                *(ushort*)((char*)xn + swz(n, c * 2)) = f2bf(vv[e] * gmm + btt);
            }
        }
    }
    __syncthreads();

    if (m < 2) {
        // ---- q/k: D[n][o] = xn[n][c] * W^T ----
        const float* bias = m ? bk : bq;
        const float scl = m ? 1.0f : 0.125f * LOG2E;   // q in exp2 domain
        bf16x8 ax0 = ldfrag(xn, (w << 4) + q16, (g << 4));
        bf16x8 ax1 = ldfrag(xn, (w << 4) + q16, 64 + (g << 4));
#pragma unroll
        for (int ot = 0; ot < 4; ++ot) {
            f32x4 acc = {0.f, 0.f, 0.f, 0.f};
            bf16x8 b0 = ldfrag(Wl, (ot << 4) + q16, (g << 4));
            bf16x8 b1 = ldfrag(Wl, (ot << 4) + q16, 64 + (g << 4));
            acc = __builtin_amdgcn_mfma_f32_16x16x32_bf16(ax0, b0, acc, 0, 0, 0);
            acc = __builtin_amdgcn_mfma_f32_16x16x32_bf16(ax1, b1, acc, 0, 0, 0);
            float bs = bias[(ot << 4) + q16];
#pragma unroll
            for (int r = 0; r < 4; ++r)
                *(ushort*)((char*)ob + swz((w << 4) + (g << 2) + r, ((ot << 4) + q16) << 1)) =
                    f2bf((acc[r] + bs) * scl);
        }
        __syncthreads();
        // ---- blocked store: ob[n][c] -> fragment chunks ----
        ushort* dst = (m ? kg : qg) + (((size_t)b) << 18);
#pragma unroll
        for (int i = 0; i < 2; ++i) {
            const int G = tid + (i << 8);            // 0..511
            const int lane_ = G & 63;
            const int h = (G >> 6) & 1;
            const int colb = (h << 5) + ((lane_ >> 4) << 3);   // ushorts
            if (m == 0) {
                const int qgi = (G >> 7) & 1;
                const int qgl = G >> 8;              // 0..1 (two 32-q groups)
                const int row = (qgl << 5) + (qgi << 4) + (lane_ & 15);
                int4 d = *(const int4*)((char*)ob + swz(row, colb << 1));
                *(int4*)(dst + (((size_t)(n0 >> 5) + qgl) << 11)
                             + ((size_t)((((qgi << 1) + h) << 6) + lane_) << 3)) = d;
            } else {
                const int nt = G >> 7;               // 0..3
                const int row = (nt << 4) + (lane_ & 15);
                int4 d = *(const int4*)((char*)ob + swz(row, colb << 1));
                *(int4*)(dst + ((size_t)(n0 >> 6) << 12)
                             + ((size_t)((((nt << 1) + h) << 6) + lane_) << 3)) = d;
            }
        }
    } else {
        // ---- v: D[o][n] = Wv * xn^T ----
        bf16x8 aw0 = ldfrag(Wl, (w << 4) + q16, (g << 4));
        bf16x8 aw1 = ldfrag(Wl, (w << 4) + q16, 64 + (g << 4));
#pragma unroll
        for (int nt = 0; nt < 4; ++nt) {
            f32x4 acc = {0.f, 0.f, 0.f, 0.f};
            bf16x8 b0 = ldfrag(xn, (nt << 4) + q16, (g << 4));
            bf16x8 b1 = ldfrag(xn, (nt << 4) + q16, 64 + (g << 4));
            acc = __builtin_amdgcn_mfma_f32_16x16x32_bf16(aw0, b0, acc, 0, 0, 0);
            acc = __builtin_amdgcn_mfma_f32_16x16x32_bf16(aw1, b1, acc, 0, 0, 0);
#pragma unroll
            for (int r = 0; r < 4; ++r) {
                float bs = bv[(w << 4) + (g << 2) + r];
                *(ushort*)((char*)ob + swz((w << 4) + (g << 2) + r, ((nt << 4) + q16) << 1)) =
                    f2bf(acc[r] + bs);
            }
        }
        __syncthreads();
        // ---- blocked store: ob[c][n_local] -> fragment chunks ----
        ushort* dst = vg + (((size_t)b) << 18) + ((size_t)(n0 >> 6) << 12);
#pragma unroll
        for (int i = 0; i < 2; ++i) {
            const int G = tid + (i << 8);            // 0..511
            const int lane_ = G & 63;
            const int h = (G >> 6) & 1;
            const int ct = G >> 7;                   // 0..3
            const int row = (ct << 4) + (lane_ & 15);        // channel
            const int colb = (h << 5) + ((lane_ >> 4) << 3); // key-local
            int4 d = *(const int4*)((char*)ob + swz(row, colb << 1));
            *(int4*)(dst + ((size_t)((((ct << 1) + h) << 6) + lane_) << 3)) = d;
        }
    }
}

// ---------------------------------------------------------------------------
// Kernel 3: attention, softmax-free (P = 2^s), K-split x8 — r14 structure
// (proven best) + T5: s_setprio(1) around the MFMA clusters. Our regime
// matches m191's positive case (barrier-free blocks, waves at independent
// phases): the scheduler favors MFMA-ready waves over exp2/pack-grinding
// ones. Zero register/schedule impact.
// ---------------------------------------------------------------------------
#define LOADK(KF, KT)                                                          \
    _Pragma("unroll") for (int nt = 0; nt < 4; ++nt)                           \
    _Pragma("unroll") for (int h = 0; h < 2; ++h)                              \
        KF[nt][h] = *(const bf16x8*)(kp + (((size_t)(KT)) << 12) +             \
                     ((size_t)((((nt << 1) + h) << 6) + lane) << 3));

#define STEP(KF, KFN, KT, PREF)                                                \
  do {                                                                         \
    bf16x8 vf[4][2];                                                           \
    _Pragma("unroll") for (int ct = 0; ct < 4; ++ct)                           \
    _Pragma("unroll") for (int h = 0; h < 2; ++h)                              \
        vf[ct][h] = *(const bf16x8*)(vp + (((size_t)(KT)) << 12) +             \
                     ((size_t)((((ct << 1) + h) << 6) + lane) << 3));          \
    if (PREF) { LOADK(KFN, (KT) + 1); }                                        \
    f32x4 s_[4][2];                                                            \
    __builtin_amdgcn_s_setprio(1);                                             \
    _Pragma("unroll") for (int nt = 0; nt < 4; ++nt)                           \
    _Pragma("unroll") for (int qgi = 0; qgi < 2; ++qgi) {                      \
        f32x4 z = {0.f, 0.f, 0.f, 0.f};                                        \
        z = __builtin_amdgcn_mfma_f32_16x16x32_bf16(KF[nt][0], aq[qgi][0], z, 0, 0, 0); \
        z = __builtin_amdgcn_mfma_f32_16x16x32_bf16(KF[nt][1], aq[qgi][1], z, 0, 0, 0); \
        s_[nt][qgi] = z;                                                       \
    }                                                                          \
    __builtin_amdgcn_s_setprio(0);                                             \
    _Pragma("unroll") for (int qgi = 0; qgi < 2; ++qgi) {                      \
        _Pragma("unroll") for (int nt = 0; nt < 4; ++nt) {                     \
            float p0 = exp2f(s_[nt][qgi][0]);                                  \
            float p1 = exp2f(s_[nt][qgi][1]);                                  \
            float p2 = exp2f(s_[nt][qgi][2]);                                  \
            float p3 = exp2f(s_[nt][qgi][3]);                                  \
            l_[qgi] += (p0 + p1) + (p2 + p3);                                  \
            float2 t01; t01.x = p0; t01.y = p1;                                \
            float2 t23; t23.x = p2; t23.y = p3;                                \
            __hip_bfloat162 b01 = __float22bfloat162_rn(t01);                  \
            __hip_bfloat162 b23 = __float22bfloat162_rn(t23);                  \
            uint2 pk; pk.x = *(uint32_t*)&b01; pk.y = *(uint32_t*)&b23;        \
            *(uint2*)((char*)Pw + swz((qgi << 4) + q16, (nt << 5) + (lg << 3))) = pk; \
        }                                                                      \
    }                                                                          \
    asm volatile("" ::: "memory");                                             \
    bf16x8 pb[2][2];                                                           \
    _Pragma("unroll") for (int qgi = 0; qgi < 2; ++qgi) {                      \
        pb[qgi][0] = ldfrag(Pw, (qgi << 4) + q16, (lg << 4));                  \
        pb[qgi][1] = ldfrag(Pw, (qgi << 4) + q16, 64 + (lg << 4));             \
    }                                                                          \
    __builtin_amdgcn_s_setprio(1);                                             \
    _Pragma("unroll") for (int ct = 0; ct < 4; ++ct)                           \
    _Pragma("unroll") for (int qgi = 0; qgi < 2; ++qgi) {                      \
        f32x4 o = o_[ct][qgi];                                                 \
        o = __builtin_amdgcn_mfma_f32_16x16x32_bf16(vf[ct][0], pb[qgi][0], o, 0, 0, 0); \
        o = __builtin_amdgcn_mfma_f32_16x16x32_bf16(vf[ct][1], pb[qgi][1], o, 0, 0, 0); \
        o_[ct][qgi] = o;                                                       \
    }                                                                          \
    __builtin_amdgcn_s_setprio(0);                                             \
  } while (0)

__global__ __launch_bounds__(256) void attn_mfma_kernel(
    const ushort* __restrict__ qg, const ushort* __restrict__ kg,
    const ushort* __restrict__ vg,
    ushort* __restrict__ opart, float* __restrict__ lpart)
{
    __shared__ ushort Ps[4][32 * 64];   // per-wave P arena [q][key], 128B swz rows

    const int tid = threadIdx.x;
    const int w = tid >> 6, lane = tid & 63, lg = lane >> 4, q16 = lane & 15;
    // bijective XCD swizzle: 1024 wg = 8 xcd chunks of 128
    const int logical = ((blockIdx.x & 7) << 7) + (blockIdx.x >> 3);
    const int ks = logical & 7;
    const int qb = (logical >> 3) & 31;       // 32 q-blocks of 128
    const int b  = logical >> 8;
    const int q0 = (qb << 7) + (w << 5);      // wave's 32 q
    // blocked bases
    const ushort* qp = qg + (((size_t)b) << 18) + ((size_t)((qb << 2) + w) << 11);
    const ushort* kp = kg + (((size_t)b) << 18) + ((size_t)ks << 15);
    const ushort* vp = vg + (((size_t)b) << 18) + ((size_t)ks << 15);
    ushort* Pw = Ps[w];

    // hoist Q B-fragments (32 q x 64 c): contiguous lane-linear chunks
    bf16x8 aq[2][2];
#pragma unroll
    for (int qgi = 0; qgi < 2; ++qgi)
#pragma unroll
        for (int h = 0; h < 2; ++h)
            aq[qgi][h] = *(const bf16x8*)(qp + ((size_t)((((qgi << 1) + h) << 6) + lane) << 3));

    float l_[2] = {0.f, 0.f};
    f32x4 o_[4][2];                       // [ct][qgi]
#pragma unroll
    for (int ct = 0; ct < 4; ++ct)
#pragma unroll
        for (int qgi = 0; qgi < 2; ++qgi) o_[ct][qgi] = (f32x4){0.f, 0.f, 0.f, 0.f};

    // statically-named K register double buffer (no runtime indexing!)
    bf16x8 kfA[4][2], kfB[4][2];
    LOADK(kfA, 0);

#pragma unroll 1
    for (int kt2 = 0; kt2 < 8; kt2 += 2) {
        STEP(kfA, kfB, kt2, true);
        STEP(kfB, kfA, kt2 + 1, (kt2 + 1) < 7);
    }

    // deferred l reduction (once, not per tile)
#pragma unroll
    for (int qgi = 0; qgi < 2; ++qgi) {
        l_[qgi] += __shfl_xor(l_[qgi], 16);
        l_[qgi] += __shfl_xor(l_[qgi], 32);
    }

    // ---- store O~ wave-blocked: opart[bs][qw][ct*2+qgi][lane][4] ----
    const size_t bs = (size_t)(b * NSPLIT + ks);
    const int qw = (qb << 2) + w;
    ushort* ob = opart + (((bs << 7) + qw) << 11);   // 2048 ushorts per (bs,qw)
#pragma unroll
    for (int ct = 0; ct < 4; ++ct)
#pragma unroll
        for (int qgi = 0; qgi < 2; ++qgi) {
            ushort4 h;
            h.x = f2bf(o_[ct][qgi][0]);
            h.y = f2bf(o_[ct][qgi][1]);
            h.z = f2bf(o_[ct][qgi][2]);
            h.w = f2bf(o_[ct][qgi][3]);
            *(ushort4*)(ob + (((((ct << 1) + qgi) << 6) + lane) << 2)) = h;
        }
    if (lg == 0) {
#pragma unroll
        for (int qgi = 0; qgi < 2; ++qgi) {
            const int n = q0 + (qgi << 4) + q16;
            lpart[bs * 4096 + n] = l_[qgi];
        }
    }
}

// ---------------------------------------------------------------------------
// Kernel 4: split-combine (plain sums) + output projection + bias + residual.
// Grid 256; XCD-affinity decode matched to attn's writer swizzle (r13 win);
// wave-blocked opart reads (r14 win).
// ---------------------------------------------------------------------------
__global__ __launch_bounds__(256) void combine_kernel(
    const ushort* __restrict__ opart, const float* __restrict__ lpart,
    const float* __restrict__ x, const float* __restrict__ Wp,
    const float* __restrict__ bp, float* __restrict__ out)
{
    __shared__ ushort Obf[64 * 64];    // combined O [n][c] bf16 swizzled
    __shared__ ushort Wps[64 * 64];    // Wp [oc][c] bf16 swizzled
    __shared__ float as_[64];          // 1/sum_l per n_local

    const int tid = threadIdx.x;
    const int w = tid >> 6, lane = tid & 63, lg = lane >> 4, q16 = lane & 15;
    const int g = lg;
    const int xcd = blockIdx.x & 7, idx = blockIdx.x >> 3;   // idx 0..31
    const int b = xcd >> 1;
    const int n0 = ((((xcd & 1) << 5) + idx) << 6);          // ntile*64

    {
        const int row = tid >> 2, cb = (tid & 3) << 4;
#pragma unroll
        for (int j = 0; j < 4; ++j) {
            float4 v = *(const float4*)(Wp + row * 64 + cb + j * 4);
            ushort4 h; h.x = f2bf(v.x); h.y = f2bf(v.y); h.z = f2bf(v.z); h.w = f2bf(v.w);
            *(ushort4*)((char*)Wps + swz(row, (cb + j * 4) * 2)) = h;
        }
    }
    if (tid < 64) {
        const int n = n0 + tid;
        float d = 0.f;
#pragma unroll
        for (int s = 0; s < NSPLIT; ++s)
            d += lpart[(size_t)(b * NSPLIT + s) * 4096 + n];
        as_[tid] = 1.0f / d;
    }
    __syncthreads();

    // ---- accumulate splits from wave-blocked opart; warp w owns ct=w ----
    {
        const int qw0 = n0 >> 5;          // two 32-q groups per 64-n tile
        float acc[2][2][4];
#pragma unroll
        for (int qwi = 0; qwi < 2; ++qwi)
#pragma unroll
            for (int qgi = 0; qgi < 2; ++qgi)
#pragma unroll
                for (int r = 0; r < 4; ++r) acc[qwi][qgi][r] = 0.f;
#pragma unroll
        for (int s = 0; s < NSPLIT; ++s) {
            const size_t bs = (size_t)(b * NSPLIT + s);
#pragma unroll
            for (int qwi = 0; qwi < 2; ++qwi)
#pragma unroll
                for (int qgi = 0; qgi < 2; ++qgi) {
                    uint2 d = *(const uint2*)(opart + (((bs << 7) + qw0 + qwi) << 11)
                                              + (((((w << 1) + qgi) << 6) + lane) << 2));
                    acc[qwi][qgi][0] += bf2f((ushort)(d.x & 0xffffu));
                    acc[qwi][qgi][1] += bf2f((ushort)(d.x >> 16));
                    acc[qwi][qgi][2] += bf2f((ushort)(d.y & 0xffffu));
                    acc[qwi][qgi][3] += bf2f((ushort)(d.y >> 16));
                }
        }
        // write into Obf[n][c] swizzled: c = w*16 + lg*4 + r
        const int c0b = ((w << 4) + (lg << 2)) << 1;   // byte offset of c0
#pragma unroll
        for (int qwi = 0; qwi < 2; ++qwi)
#pragma unroll
            for (int qgi = 0; qgi < 2; ++qgi) {
                const int nl = (qwi << 5) + (qgi << 4) + q16;
                const float a = as_[nl];
                ushort4 h;
                h.x = f2bf(acc[qwi][qgi][0] * a);
                h.y = f2bf(acc[qwi][qgi][1] * a);
                h.z = f2bf(acc[qwi][qgi][2] * a);
                h.w = f2bf(acc[qwi][qgi][3] * a);
                *(ushort4*)((char*)Obf + swz(nl, c0b)) = h;
            }
    }
    __syncthreads();

    {
        bf16x8 aw0 = ldfrag(Wps, (w << 4) + q16, (g << 4));
        bf16x8 aw1 = ldfrag(Wps, (w << 4) + q16, 64 + (g << 4));
        float bpv[4];
#pragma unroll
        for (int r = 0; r < 4; ++r) bpv[r] = bp[(w << 4) + (g << 2) + r];
#pragma unroll
        for (int qt = 0; qt < 4; ++qt) {
            f32x4 d = {0.f, 0.f, 0.f, 0.f};
            bf16x8 b0 = ldfrag(Obf, (qt << 4) + q16, (g << 4));
            bf16x8 b1 = ldfrag(Obf, (qt << 4) + q16, 64 + (g << 4));
            d = __builtin_amdgcn_mfma_f32_16x16x32_bf16(aw0, b0, d, 0, 0, 0);
            d = __builtin_amdgcn_mfma_f32_16x16x32_bf16(aw1, b1, d, 0, 0, 0);
#pragma unroll
            for (int r = 0; r < 4; ++r) {
                int oc = (w << 4) + (g << 2) + r;
                size_t addr = (((size_t)(b * CH + oc)) << 12) + n0 + (qt << 4) + q16;
                out[addr] = d[r] + bpv[r] + x[addr];
            }
        }
    }
}

// ---------------------------------------------------------------------------
extern "C" void kernel_launch(void* const* d_in, const int* in_sizes, int n_in,
                              void* d_out, int out_size, void* d_ws, size_t ws_size,
                              hipStream_t stream) {
    const float* x     = (const float*)d_in[0];
    const float* gamma = (const float*)d_in[1];
    const float* beta  = (const float*)d_in[2];
    const float* Wq    = (const float*)d_in[3];
    const float* bq    = (const float*)d_in[4];
    const float* Wk    = (const float*)d_in[5];
    const float* bk    = (const float*)d_in[6];
    const float* Wv    = (const float*)d_in[7];
    const float* bv    = (const float*)d_in[8];
    const float* Wp    = (const float*)d_in[9];
    const float* bp    = (const float*)d_in[10];
    float* out = (float*)d_out;

    float2* part = (float2*)d_ws;                      // 256 float2 = 2KB
    ushort* q_t = (ushort*)((char*)d_ws + 4096);       // blocked Q, 2MB
    ushort* k_t = q_t + (size_t)BATCH * NPOS * CH;     // blocked K, 2MB
    ushort* v_t = k_t + (size_t)BATCH * NPOS * CH;     // blocked V, 2MB
    ushort* opart = (ushort*)((char*)d_ws + 4096 + (size_t)3 * BATCH * NPOS * CH * 2);
    float* lpart = (float*)((char*)opart + (size_t)BATCH * NSPLIT * CH * NPOS * 2);

    hipLaunchKernelGGL(gn_part_kernel, dim3(256), dim3(256), 0, stream, x, part);
    hipLaunchKernelGGL(qkv_mfma_kernel, dim3(768), dim3(256), 0, stream,
                       x, part, gamma, beta, Wq, bq, Wk, bk, Wv, bv, q_t, k_t, v_t);
    hipLaunchKernelGGL(attn_mfma_kernel, dim3(1024), dim3(256), 0, stream,
                       q_t, k_t, v_t, opart, lpart);
    hipLaunchKernelGGL(combine_kernel, dim3(BATCH * 64), dim3(256), 0, stream,
                       opart, lpart, x, Wp, bp, out);
}

// Round 16
// 50.779 us; speedup vs baseline: 1.2390x; 1.2390x over previous
//
#include <hip/hip_runtime.h>
#include <hip/hip_bf16.h>
#include <math.h>

#define BATCH 4
#define CH    64
#define NPOS  4096   // 64*64
#define NGRP  8
#define CPG   8      // CH / NGRP
#define GEPS  1e-5f
#define NSPLIT 8     // K-dim split of attention
#define LOG2E 1.4426950408889634f

typedef __attribute__((ext_vector_type(8))) short bf16x8;   // 8 bf16 = 4 VGPRs
typedef __attribute__((ext_vector_type(4))) float f32x4;

// float -> bf16 bits (round-to-nearest-even)
__device__ __forceinline__ ushort f2bf(float f) {
    union { float f; uint32_t u; } v; v.f = f;
    uint32_t r = v.u + 0x7fffu + ((v.u >> 16) & 1u);
    return (ushort)(r >> 16);
}
__device__ __forceinline__ float bf2f(ushort u) {
    union { uint32_t u; float f; } v; v.u = ((uint32_t)u) << 16; return v.f;
}

// XOR swizzle within a 128B row: logical (row, byteInRow) -> physical byte offset
__device__ __forceinline__ uint32_t swz(uint32_t row, uint32_t byteInRow) {
    return (row << 7) + (byteInRow ^ ((row & 7u) << 4));
}

// 16B ds_read of an MFMA fragment slice
__device__ __forceinline__ bf16x8 ldfrag(const ushort* base, int row, int kbyte) {
    return *(const bf16x8*)((const char*)base + swz(row, kbyte));
}

// ---------------------------------------------------------------------------
// Kernel 1: GroupNorm partial sums. Grid 256: block = (bg, slice of 4096).
// ---------------------------------------------------------------------------
__global__ __launch_bounds__(256) void gn_part_kernel(const float* __restrict__ x,
                                                      float2* __restrict__ part) {
    const int blk = blockIdx.x;                      // bg*8 + slice
    const float4* xp4 = (const float4*)(x + (size_t)blk * 4096);
    float s1 = 0.f, s2 = 0.f;
    for (int i = threadIdx.x; i < 1024; i += 256) {
        float4 t = xp4[i];
        s1 += t.x + t.y + t.z + t.w;
        s2 += t.x * t.x + t.y * t.y + t.z * t.z + t.w * t.w;
    }
    __shared__ float sh1[256], sh2[256];
    const int tid = threadIdx.x;
    sh1[tid] = s1; sh2[tid] = s2;
    __syncthreads();
    for (int off = 128; off > 0; off >>= 1) {
        if (tid < off) { sh1[tid] += sh1[tid + off]; sh2[tid] += sh2[tid + off]; }
        __syncthreads();
    }
    if (tid == 0) { float2 r; r.x = sh1[0]; r.y = sh2[0]; part[blk] = r; }
}

// ---------------------------------------------------------------------------
// Kernel 2: fused GN-finish + GroupNorm-apply + ONE of {q,k,v} 1x1 conv.
// Grid 768. Outputs in FRAGMENT-BLOCKED layout (contiguous lane-linear 1KB
// chunks per MFMA fragment):
//   Q_blk[b][qgrp(128 of 32q)][qgi(2)][h(2)][lane(64)][8]
//   K_blk[b][kt(64)][nt(4)][h(2)][lane(64)][8]
//   V_blk[b][kt(64)][ct(4)][h(2)][lane(64)][8]
// q folds bias and 0.125*log2e (exp2-domain softmax).
// ---------------------------------------------------------------------------
__global__ __launch_bounds__(256) void qkv_mfma_kernel(
    const float* __restrict__ x, const float2* __restrict__ part,
    const float* __restrict__ gamma, const float* __restrict__ beta,
    const float* __restrict__ Wq, const float* __restrict__ bq,
    const float* __restrict__ Wk, const float* __restrict__ bk,
    const float* __restrict__ Wv, const float* __restrict__ bv,
    ushort* __restrict__ qg, ushort* __restrict__ kg, ushort* __restrict__ vg)
{
    __shared__ ushort xn[64 * 64];     // [n][c] swizzled bf16
    __shared__ ushort Wl[64 * 64];     // W [o][c] swizzled bf16
    __shared__ ushort ob[64 * 64];     // output bounce
    __shared__ float st[16];           // 8 groups * {mean, rstd} for this b

    const int tid = threadIdx.x;
    const int w = tid >> 6, lane = tid & 63, g = lane >> 4, q16 = lane & 15;
    const int m = blockIdx.x >> 8;               // 0=q 1=k 2=v
    const int bidx = blockIdx.x & 255;
    const int b = bidx >> 6, n0 = (bidx & 63) << 6;

    const float* W = (m == 0) ? Wq : (m == 1) ? Wk : Wv;

    {
        const int row = tid >> 2, cb = (tid & 3) << 4;
#pragma unroll
        for (int j = 0; j < 4; ++j) {
            float4 v = *(const float4*)(W + row * 64 + cb + j * 4);
            ushort4 h; h.x = f2bf(v.x); h.y = f2bf(v.y); h.z = f2bf(v.z); h.w = f2bf(v.w);
            *(ushort4*)((char*)Wl + swz(row, (cb + j * 4) * 2)) = h;
        }
    }
    if (tid < 64) {
        float2 p = part[b * 64 + tid];
        float s1 = p.x, s2 = p.y;
        s1 += __shfl_xor(s1, 1); s2 += __shfl_xor(s2, 1);
        s1 += __shfl_xor(s1, 2); s2 += __shfl_xor(s2, 2);
        s1 += __shfl_xor(s1, 4); s2 += __shfl_xor(s2, 4);
        if ((tid & 7) == 0) {
            const float inv = 1.0f / (float)(CPG * NPOS);
            float mean = s1 * inv;
            float var  = s2 * inv - mean * mean;
            st[(tid >> 3) * 2]     = mean;
            st[(tid >> 3) * 2 + 1] = rsqrtf(var + GEPS);
        }
    }
    __syncthreads();

    {
        const int c = tid >> 2, nb = (tid & 3) << 4;
        const float mean = st[(c >> 3) * 2];
        const float rstd = st[(c >> 3) * 2 + 1];
        const float gmm = gamma[c] * rstd;
        const float btt = beta[c] - mean * gmm;
        const float* xp = x + (((size_t)(b * CH + c)) << 12) + n0 + nb;
#pragma unroll
        for (int j = 0; j < 4; ++j) {
            float4 v = *(const float4*)(xp + j * 4);
            float vv[4] = {v.x, v.y, v.z, v.w};
#pragma unroll
            for (int e = 0; e < 4; ++e) {
                int n = nb + j * 4 + e;
                *(ushort*)((char*)xn + swz(n, c * 2)) = f2bf(vv[e] * gmm + btt);
            }
        }
    }
    __syncthreads();

    if (m < 2) {
        // ---- q/k: D[n][o] = xn[n][c] * W^T ----
        const float* bias = m ? bk : bq;
        const float scl = m ? 1.0f : 0.125f * LOG2E;   // q in exp2 domain
        bf16x8 ax0 = ldfrag(xn, (w << 4) + q16, (g << 4));
        bf16x8 ax1 = ldfrag(xn, (w << 4) + q16, 64 + (g << 4));
#pragma unroll
        for (int ot = 0; ot < 4; ++ot) {
            f32x4 acc = {0.f, 0.f, 0.f, 0.f};
            bf16x8 b0 = ldfrag(Wl, (ot << 4) + q16, (g << 4));
            bf16x8 b1 = ldfrag(Wl, (ot << 4) + q16, 64 + (g << 4));
            acc = __builtin_amdgcn_mfma_f32_16x16x32_bf16(ax0, b0, acc, 0, 0, 0);
            acc = __builtin_amdgcn_mfma_f32_16x16x32_bf16(ax1, b1, acc, 0, 0, 0);
            float bs = bias[(ot << 4) + q16];
#pragma unroll
            for (int r = 0; r < 4; ++r)
                *(ushort*)((char*)ob + swz((w << 4) + (g << 2) + r, ((ot << 4) + q16) << 1)) =
                    f2bf((acc[r] + bs) * scl);
        }
        __syncthreads();
        // ---- blocked store: ob[n][c] -> fragment chunks ----
        ushort* dst = (m ? kg : qg) + (((size_t)b) << 18);
#pragma unroll
        for (int i = 0; i < 2; ++i) {
            const int G = tid + (i << 8);            // 0..511
            const int lane_ = G & 63;
            const int h = (G >> 6) & 1;
            const int colb = (h << 5) + ((lane_ >> 4) << 3);   // ushorts
            if (m == 0) {
                const int qgi = (G >> 7) & 1;
                const int qgl = G >> 8;              // 0..1 (two 32-q groups)
                const int row = (qgl << 5) + (qgi << 4) + (lane_ & 15);
                int4 d = *(const int4*)((char*)ob + swz(row, colb << 1));
                *(int4*)(dst + (((size_t)(n0 >> 5) + qgl) << 11)
                             + ((size_t)((((qgi << 1) + h) << 6) + lane_) << 3)) = d;
            } else {
                const int nt = G >> 7;               // 0..3
                const int row = (nt << 4) + (lane_ & 15);
                int4 d = *(const int4*)((char*)ob + swz(row, colb << 1));
                *(int4*)(dst + ((size_t)(n0 >> 6) << 12)
                             + ((size_t)((((nt << 1) + h) << 6) + lane_) << 3)) = d;
            }
        }
    } else {
        // ---- v: D[o][n] = Wv * xn^T ----
        bf16x8 aw0 = ldfrag(Wl, (w << 4) + q16, (g << 4));
        bf16x8 aw1 = ldfrag(Wl, (w << 4) + q16, 64 + (g << 4));
#pragma unroll
        for (int nt = 0; nt < 4; ++nt) {
            f32x4 acc = {0.f, 0.f, 0.f, 0.f};
            bf16x8 b0 = ldfrag(xn, (nt << 4) + q16, (g << 4));
            bf16x8 b1 = ldfrag(xn, (nt << 4) + q16, 64 + (g << 4));
            acc = __builtin_amdgcn_mfma_f32_16x16x32_bf16(aw0, b0, acc, 0, 0, 0);
            acc = __builtin_amdgcn_mfma_f32_16x16x32_bf16(aw1, b1, acc, 0, 0, 0);
#pragma unroll
            for (int r = 0; r < 4; ++r) {
                float bs = bv[(w << 4) + (g << 2) + r];
                *(ushort*)((char*)ob + swz((w << 4) + (g << 2) + r, ((nt << 4) + q16) << 1)) =
                    f2bf(acc[r] + bs);
            }
        }
        __syncthreads();
        // ---- blocked store: ob[c][n_local] -> fragment chunks ----
        ushort* dst = vg + (((size_t)b) << 18) + ((size_t)(n0 >> 6) << 12);
#pragma unroll
        for (int i = 0; i < 2; ++i) {
            const int G = tid + (i << 8);            // 0..511
            const int lane_ = G & 63;
            const int h = (G >> 6) & 1;
            const int ct = G >> 7;                   // 0..3
            const int row = (ct << 4) + (lane_ & 15);        // channel
            const int colb = (h << 5) + ((lane_ >> 4) << 3); // key-local
            int4 d = *(const int4*)((char*)ob + swz(row, colb << 1));
            *(int4*)(dst + ((size_t)((((ct << 1) + h) << 6) + lane_) << 3)) = d;
        }
    }
}

// ---------------------------------------------------------------------------
// Kernel 3: attention, softmax-free (P = 2^s), K-split x8 — r14 structure
// (proven best, 50.6us total): 1024 blocks x 4 waves; 32 q/wave; blocked-
// layout direct-L2 fragment loads; named K dbuf kfA/kfB; deferred l reduce;
// wave-blocked O~ stores. NO setprio (r15: +12 VGPR -> occupancy cliff).
// ---------------------------------------------------------------------------
#define LOADK(KF, KT)                                                          \
    _Pragma("unroll") for (int nt = 0; nt < 4; ++nt)                           \
    _Pragma("unroll") for (int h = 0; h < 2; ++h)                              \
        KF[nt][h] = *(const bf16x8*)(kp + (((size_t)(KT)) << 12) +             \
                     ((size_t)((((nt << 1) + h) << 6) + lane) << 3));

#define STEP(KF, KFN, KT, PREF)                                                \
  do {                                                                         \
    bf16x8 vf[4][2];                                                           \
    _Pragma("unroll") for (int ct = 0; ct < 4; ++ct)                           \
    _Pragma("unroll") for (int h = 0; h < 2; ++h)                              \
        vf[ct][h] = *(const bf16x8*)(vp + (((size_t)(KT)) << 12) +             \
                     ((size_t)((((ct << 1) + h) << 6) + lane) << 3));          \
    if (PREF) { LOADK(KFN, (KT) + 1); }                                        \
    f32x4 s_[4][2];                                                            \
    _Pragma("unroll") for (int nt = 0; nt < 4; ++nt)                           \
    _Pragma("unroll") for (int qgi = 0; qgi < 2; ++qgi) {                      \
        f32x4 z = {0.f, 0.f, 0.f, 0.f};                                        \
        z = __builtin_amdgcn_mfma_f32_16x16x32_bf16(KF[nt][0], aq[qgi][0], z, 0, 0, 0); \
        z = __builtin_amdgcn_mfma_f32_16x16x32_bf16(KF[nt][1], aq[qgi][1], z, 0, 0, 0); \
        s_[nt][qgi] = z;                                                       \
    }                                                                          \
    _Pragma("unroll") for (int qgi = 0; qgi < 2; ++qgi) {                      \
        _Pragma("unroll") for (int nt = 0; nt < 4; ++nt) {                     \
            float p0 = exp2f(s_[nt][qgi][0]);                                  \
            float p1 = exp2f(s_[nt][qgi][1]);                                  \
            float p2 = exp2f(s_[nt][qgi][2]);                                  \
            float p3 = exp2f(s_[nt][qgi][3]);                                  \
            l_[qgi] += (p0 + p1) + (p2 + p3);                                  \
            float2 t01; t01.x = p0; t01.y = p1;                                \
            float2 t23; t23.x = p2; t23.y = p3;                                \
            __hip_bfloat162 b01 = __float22bfloat162_rn(t01);                  \
            __hip_bfloat162 b23 = __float22bfloat162_rn(t23);                  \
            uint2 pk; pk.x = *(uint32_t*)&b01; pk.y = *(uint32_t*)&b23;        \
            *(uint2*)((char*)Pw + swz((qgi << 4) + q16, (nt << 5) + (lg << 3))) = pk; \
        }                                                                      \
    }                                                                          \
    asm volatile("" ::: "memory");                                             \
    bf16x8 pb[2][2];                                                           \
    _Pragma("unroll") for (int qgi = 0; qgi < 2; ++qgi) {                      \
        pb[qgi][0] = ldfrag(Pw, (qgi << 4) + q16, (lg << 4));                  \
        pb[qgi][1] = ldfrag(Pw, (qgi << 4) + q16, 64 + (lg << 4));             \
    }                                                                          \
    _Pragma("unroll") for (int ct = 0; ct < 4; ++ct)                           \
    _Pragma("unroll") for (int qgi = 0; qgi < 2; ++qgi) {                      \
        f32x4 o = o_[ct][qgi];                                                 \
        o = __builtin_amdgcn_mfma_f32_16x16x32_bf16(vf[ct][0], pb[qgi][0], o, 0, 0, 0); \
        o = __builtin_amdgcn_mfma_f32_16x16x32_bf16(vf[ct][1], pb[qgi][1], o, 0, 0, 0); \
        o_[ct][qgi] = o;                                                       \
    }                                                                          \
  } while (0)

__global__ __launch_bounds__(256) void attn_mfma_kernel(
    const ushort* __restrict__ qg, const ushort* __restrict__ kg,
    const ushort* __restrict__ vg,
    ushort* __restrict__ opart, float* __restrict__ lpart)
{
    __shared__ ushort Ps[4][32 * 64];   // per-wave P arena [q][key], 128B swz rows

    const int tid = threadIdx.x;
    const int w = tid >> 6, lane = tid & 63, lg = lane >> 4, q16 = lane & 15;
    // bijective XCD swizzle: 1024 wg = 8 xcd chunks of 128
    const int logical = ((blockIdx.x & 7) << 7) + (blockIdx.x >> 3);
    const int ks = logical & 7;
    const int qb = (logical >> 3) & 31;       // 32 q-blocks of 128
    const int b  = logical >> 8;
    const int q0 = (qb << 7) + (w << 5);      // wave's 32 q
    // blocked bases
    const ushort* qp = qg + (((size_t)b) << 18) + ((size_t)((qb << 2) + w) << 11);
    const ushort* kp = kg + (((size_t)b) << 18) + ((size_t)ks << 15);
    const ushort* vp = vg + (((size_t)b) << 18) + ((size_t)ks << 15);
    ushort* Pw = Ps[w];

    // hoist Q B-fragments (32 q x 64 c): contiguous lane-linear chunks
    bf16x8 aq[2][2];
#pragma unroll
    for (int qgi = 0; qgi < 2; ++qgi)
#pragma unroll
        for (int h = 0; h < 2; ++h)
            aq[qgi][h] = *(const bf16x8*)(qp + ((size_t)((((qgi << 1) + h) << 6) + lane) << 3));

    float l_[2] = {0.f, 0.f};
    f32x4 o_[4][2];                       // [ct][qgi]
#pragma unroll
    for (int ct = 0; ct < 4; ++ct)
#pragma unroll
        for (int qgi = 0; qgi < 2; ++qgi) o_[ct][qgi] = (f32x4){0.f, 0.f, 0.f, 0.f};

    // statically-named K register double buffer (no runtime indexing!)
    bf16x8 kfA[4][2], kfB[4][2];
    LOADK(kfA, 0);

#pragma unroll 1
    for (int kt2 = 0; kt2 < 8; kt2 += 2) {
        STEP(kfA, kfB, kt2, true);
        STEP(kfB, kfA, kt2 + 1, (kt2 + 1) < 7);
    }

    // deferred l reduction (once, not per tile)
#pragma unroll
    for (int qgi = 0; qgi < 2; ++qgi) {
        l_[qgi] += __shfl_xor(l_[qgi], 16);
        l_[qgi] += __shfl_xor(l_[qgi], 32);
    }

    // ---- store O~ wave-blocked: opart[bs][qw][ct*2+qgi][lane][4] ----
    const size_t bs = (size_t)(b * NSPLIT + ks);
    const int qw = (qb << 2) + w;
    ushort* ob = opart + (((bs << 7) + qw) << 11);   // 2048 ushorts per (bs,qw)
#pragma unroll
    for (int ct = 0; ct < 4; ++ct)
#pragma unroll
        for (int qgi = 0; qgi < 2; ++qgi) {
            ushort4 h;
            h.x = f2bf(o_[ct][qgi][0]);
            h.y = f2bf(o_[ct][qgi][1]);
            h.z = f2bf(o_[ct][qgi][2]);
            h.w = f2bf(o_[ct][qgi][3]);
            *(ushort4*)(ob + (((((ct << 1) + qgi) << 6) + lane) << 2)) = h;
        }
    if (lg == 0) {
#pragma unroll
        for (int qgi = 0; qgi < 2; ++qgi) {
            const int n = q0 + (qgi << 4) + q16;
            lpart[bs * 4096 + n] = l_[qgi];
        }
    }
}

// ---------------------------------------------------------------------------
// Kernel 4: split-combine (plain sums) + output projection + bias + residual.
// Grid 256; XCD-affinity decode matched to attn's writer swizzle (r13 win);
// wave-blocked opart reads (r14 win).
// ---------------------------------------------------------------------------
__global__ __launch_bounds__(256) void combine_kernel(
    const ushort* __restrict__ opart, const float* __restrict__ lpart,
    const float* __restrict__ x, const float* __restrict__ Wp,
    const float* __restrict__ bp, float* __restrict__ out)
{
    __shared__ ushort Obf[64 * 64];    // combined O [n][c] bf16 swizzled
    __shared__ ushort Wps[64 * 64];    // Wp [oc][c] bf16 swizzled
    __shared__ float as_[64];          // 1/sum_l per n_local

    const int tid = threadIdx.x;
    const int w = tid >> 6, lane = tid & 63, lg = lane >> 4, q16 = lane & 15;
    const int g = lg;
    const int xcd = blockIdx.x & 7, idx = blockIdx.x >> 3;   // idx 0..31
    const int b = xcd >> 1;
    const int n0 = ((((xcd & 1) << 5) + idx) << 6);          // ntile*64

    {
        const int row = tid >> 2, cb = (tid & 3) << 4;
#pragma unroll
        for (int j = 0; j < 4; ++j) {
            float4 v = *(const float4*)(Wp + row * 64 + cb + j * 4);
            ushort4 h; h.x = f2bf(v.x); h.y = f2bf(v.y); h.z = f2bf(v.z); h.w = f2bf(v.w);
            *(ushort4*)((char*)Wps + swz(row, (cb + j * 4) * 2)) = h;
        }
    }
    if (tid < 64) {
        const int n = n0 + tid;
        float d = 0.f;
#pragma unroll
        for (int s = 0; s < NSPLIT; ++s)
            d += lpart[(size_t)(b * NSPLIT + s) * 4096 + n];
        as_[tid] = 1.0f / d;
    }
    __syncthreads();

    // ---- accumulate splits from wave-blocked opart; warp w owns ct=w ----
    {
        const int qw0 = n0 >> 5;          // two 32-q groups per 64-n tile
        float acc[2][2][4];
#pragma unroll
        for (int qwi = 0; qwi < 2; ++qwi)
#pragma unroll
            for (int qgi = 0; qgi < 2; ++qgi)
#pragma unroll
                for (int r = 0; r < 4; ++r) acc[qwi][qgi][r] = 0.f;
#pragma unroll
        for (int s = 0; s < NSPLIT; ++s) {
            const size_t bs = (size_t)(b * NSPLIT + s);
#pragma unroll
            for (int qwi = 0; qwi < 2; ++qwi)
#pragma unroll
                for (int qgi = 0; qgi < 2; ++qgi) {
                    uint2 d = *(const uint2*)(opart + (((bs << 7) + qw0 + qwi) << 11)
                                              + (((((w << 1) + qgi) << 6) + lane) << 2));
                    acc[qwi][qgi][0] += bf2f((ushort)(d.x & 0xffffu));
                    acc[qwi][qgi][1] += bf2f((ushort)(d.x >> 16));
                    acc[qwi][qgi][2] += bf2f((ushort)(d.y & 0xffffu));
                    acc[qwi][qgi][3] += bf2f((ushort)(d.y >> 16));
                }
        }
        // write into Obf[n][c] swizzled: c = w*16 + lg*4 + r
        const int c0b = ((w << 4) + (lg << 2)) << 1;   // byte offset of c0
#pragma unroll
        for (int qwi = 0; qwi < 2; ++qwi)
#pragma unroll
            for (int qgi = 0; qgi < 2; ++qgi) {
                const int nl = (qwi << 5) + (qgi << 4) + q16;
                const float a = as_[nl];
                ushort4 h;
                h.x = f2bf(acc[qwi][qgi][0] * a);
                h.y = f2bf(acc[qwi][qgi][1] * a);
                h.z = f2bf(acc[qwi][qgi][2] * a);
                h.w = f2bf(acc[qwi][qgi][3] * a);
                *(ushort4*)((char*)Obf + swz(nl, c0b)) = h;
            }
    }
    __syncthreads();

    {
        bf16x8 aw0 = ldfrag(Wps, (w << 4) + q16, (g << 4));
        bf16x8 aw1 = ldfrag(Wps, (w << 4) + q16, 64 + (g << 4));
        float bpv[4];
#pragma unroll
        for (int r = 0; r < 4; ++r) bpv[r] = bp[(w << 4) + (g << 2) + r];
#pragma unroll
        for (int qt = 0; qt < 4; ++qt) {
            f32x4 d = {0.f, 0.f, 0.f, 0.f};
            bf16x8 b0 = ldfrag(Obf, (qt << 4) + q16, (g << 4));
            bf16x8 b1 = ldfrag(Obf, (qt << 4) + q16, 64 + (g << 4));
            d = __builtin_amdgcn_mfma_f32_16x16x32_bf16(aw0, b0, d, 0, 0, 0);
            d = __builtin_amdgcn_mfma_f32_16x16x32_bf16(aw1, b1, d, 0, 0, 0);
#pragma unroll
            for (int r = 0; r < 4; ++r) {
                int oc = (w << 4) + (g << 2) + r;
                size_t addr = (((size_t)(b * CH + oc)) << 12) + n0 + (qt << 4) + q16;
                out[addr] = d[r] + bpv[r] + x[addr];
            }
        }
    }
}

// ---------------------------------------------------------------------------
extern "C" void kernel_launch(void* const* d_in, const int* in_sizes, int n_in,
                              void* d_out, int out_size, void* d_ws, size_t ws_size,
                              hipStream_t stream) {
    const float* x     = (const float*)d_in[0];
    const float* gamma = (const float*)d_in[1];
    const float* beta  = (const float*)d_in[2];
    const float* Wq    = (const float*)d_in[3];
    const float* bq    = (const float*)d_in[4];
    const float* Wk    = (const float*)d_in[5];
    const float* bk    = (const float*)d_in[6];
    const float* Wv    = (const float*)d_in[7];
    const float* bv    = (const float*)d_in[8];
    const float* Wp    = (const float*)d_in[9];
    const float* bp    = (const float*)d_in[10];
    float* out = (float*)d_out;

    float2* part = (float2*)d_ws;                      // 256 float2 = 2KB
    ushort* q_t = (ushort*)((char*)d_ws + 4096);       // blocked Q, 2MB
    ushort* k_t = q_t + (size_t)BATCH * NPOS * CH;     // blocked K, 2MB
    ushort* v_t = k_t + (size_t)BATCH * NPOS * CH;     // blocked V, 2MB
    ushort* opart = (ushort*)((char*)d_ws + 4096 + (size_t)3 * BATCH * NPOS * CH * 2);
    float* lpart = (float*)((char*)opart + (size_t)BATCH * NSPLIT * CH * NPOS * 2);

    hipLaunchKernelGGL(gn_part_kernel, dim3(256), dim3(256), 0, stream, x, part);
    hipLaunchKernelGGL(qkv_mfma_kernel, dim3(768), dim3(256), 0, stream,
                       x, part, gamma, beta, Wq, bq, Wk, bk, Wv, bv, q_t, k_t, v_t);
    hipLaunchKernelGGL(attn_mfma_kernel, dim3(1024), dim3(256), 0, stream,
                       q_t, k_t, v_t, opart, lpart);
    hipLaunchKernelGGL(combine_kernel, dim3(BATCH * 64), dim3(256), 0, stream,
                       opart, lpart, x, Wp, bp, out);
}